// Round 18
// baseline (502.282 us; speedup 1.0000x reference)
//
#include <hip/hip_runtime.h>

#define Bc 4
#define Lc 4096
#define Dc 1024
#define LDQ 3072
#define Mc (Bc*Lc)
#define EPSc 1e-6f

typedef __bf16 bf16x8 __attribute__((ext_vector_type(8)));
typedef __bf16 bf16x4 __attribute__((ext_vector_type(4)));
typedef float f32x4 __attribute__((ext_vector_type(4)));

typedef __attribute__((address_space(3))) void lds_vt;
typedef const __attribute__((address_space(1))) void gbl_vt;

__device__ __forceinline__ void gll16(const void* g, void* l) {
  __builtin_amdgcn_global_load_lds((gbl_vt*)g, (lds_vt*)l, 16, 0, 0);
}

// ---------------- fused converts (validated) ----------------
__global__ __launch_bounds__(256) void conv3(const float* __restrict__ Q, const float* __restrict__ K,
                                             const float* __restrict__ V, __bf16* __restrict__ Y) {
  const float* src = (blockIdx.y == 0) ? Q : (blockIdx.y == 1) ? K : V;
  __bf16* dst = Y + (size_t)blockIdx.y * ((size_t)Mc * Dc);
  const int i = blockIdx.x * 256 + threadIdx.x;
  const float4 v = ((const float4*)src)[i];
  bf16x4 o;
  o[0] = (__bf16)v.x; o[1] = (__bf16)v.y; o[2] = (__bf16)v.z; o[3] = (__bf16)v.w;
  ((bf16x4*)dst)[i] = o;
}

__global__ __launch_bounds__(256) void wt_conv4(const float* __restrict__ W0, const float* __restrict__ W1,
                                                const float* __restrict__ W2, const float* __restrict__ W3,
                                                __bf16* __restrict__ T) {
  const float* W = (blockIdx.z == 0) ? W0 : (blockIdx.z == 1) ? W1 : (blockIdx.z == 2) ? W2 : W3;
  __bf16* Wt = T + (size_t)blockIdx.z * ((size_t)Dc * Dc);
  __shared__ float t[32][33];
  const int n0 = blockIdx.x << 5, k0 = blockIdx.y << 5;
  const int tx = threadIdx.x, ty = threadIdx.y;  // block (32,8)
#pragma unroll
  for (int i = 0; i < 4; ++i)
    t[ty + 8 * i][tx] = W[(size_t)(k0 + ty + 8 * i) * Dc + n0 + tx];
  __syncthreads();
#pragma unroll
  for (int i = 0; i < 4; ++i)
    Wt[(size_t)(n0 + ty + 8 * i) * Dc + k0 + tx] = (__bf16)t[tx][ty + 8 * i];
}

// ---------------- QKV GEMM: 128x128, BK=32, dbuf A-through-LDS, B global->regs ----------
// B-operand (L2-resident weights) loads straight to VGPRs: per-lane 16B k-contiguous,
// 16 rows x full 64B lines per frag -> no LDS write/read for B. LDS traffic per CU-step
// halves (192->96 KB). Values bit-identical to the r15/r17-validated kernel.
template <int FUSED>
__global__ __launch_bounds__(256, 4) void gemm128p(
    const __bf16* __restrict__ Aq_, const __bf16* __restrict__ Ak_, const __bf16* __restrict__ Av_,
    const __bf16* __restrict__ Wq_, const __bf16* __restrict__ Wk_, const __bf16* __restrict__ Wv_,
    const float* __restrict__ bq_, const float* __restrict__ bk_, const float* __restrict__ bv_,
    void* __restrict__ Cp, float* __restrict__ qsum, float* __restrict__ ksum) {
  __shared__ __bf16 As[2][128 * 32];
  const int tid = threadIdx.x;
  const int lane = tid & 63, w4 = tid >> 6;
  const int wr = w4 >> 1, wc = w4 & 1;          // 2 x 2 waves, 64x64 each
  const int lf = lane & 15, kq = lane >> 4;

  constexpr int NCT = FUSED ? 24 : 8;
  constexpr int CPX = (128 * NCT) >> 3;
  const int hwlin = blockIdx.x + (blockIdx.y << 7);
  const int swz = (hwlin & 7) * CPX + (hwlin >> 3);
  const int bx = swz / NCT, ct = swz - bx * NCT;
  const int row0 = bx << 7, col0 = ct << 7;
  const int region = FUSED ? (ct >> 3) : 0;
  const int colL = FUSED ? (col0 & 1023) : col0;

  const __bf16* Agl = FUSED ? (region == 0 ? Aq_ : (region == 1 ? Ak_ : Av_)) : Aq_;
  const __bf16* Bgl = FUSED ? (region == 0 ? Wq_ : (region == 1 ? Wk_ : Wv_)) : Wq_;
  const float* biasp = FUSED ? (region == 0 ? bq_ : (region == 1 ? bk_ : bv_)) : bq_;
  const __bf16* Ab_g = Agl + (size_t)row0 * 1024;
  const __bf16* Bb_g = Bgl + (size_t)colL * 1024;

  const int srow = (w4 << 5) + (lane >> 2);
  const int sgd = lane & 3;
  const int ssrc = (sgd ^ ((lane >> 3) & 3)) << 3;
  const size_t aoff0 = (size_t)srow * 1024 + ssrc;
  const size_t aoff1 = (size_t)(srow + 16) * 1024 + ssrc;
  const int ldst0 = srow * 32 + (sgd << 3);
  const int ldst1 = (srow + 16) * 32 + (sgd << 3);

  const int kgsw = (kq ^ ((lf >> 1) & 3)) << 3;
  const int arb = (wr * 64 + lf) * 32 + kgsw;
  // B direct-from-global row base (per-lane): row = wc*64 + n*16 + lf, k = t*32 + kq*8
  const __bf16* Bln = Bb_g + (size_t)(wc * 64 + lf) * 1024 + kq * 8;

#define STGA(T, U) do { \
    const int kb_ = (T) << 5; \
    gll16(Ab_g + aoff0 + kb_, &As[U][ldst0]); \
    gll16(Ab_g + aoff1 + kb_, &As[U][ldst1]); \
  } while (0)

  f32x4 acc[4][4] = {};

  STGA(0, 0);
  __syncthreads();

  for (int t = 0; t < 32; ++t) {
    const int u = t & 1;
    bf16x8 bfr[4];
#pragma unroll
    for (int n = 0; n < 4; ++n)                 // B: global->reg, issued first (L2 latency)
      bfr[n] = *(const bf16x8*)(Bln + (size_t)(n << 4) * 1024 + (t << 5));
    if (t < 31) STGA(t + 1, u ^ 1);             // A: streams during compute
    bf16x8 af[4];
#pragma unroll
    for (int m = 0; m < 4; ++m) af[m] = *(const bf16x8*)(&As[u][0] + arb + m * 512);
#pragma unroll
    for (int m = 0; m < 4; ++m)
#pragma unroll
      for (int n = 0; n < 4; ++n)
        acc[m][n] = __builtin_amdgcn_mfma_f32_16x16x32_bf16(bfr[n], af[m], acc[m][n], 0, 0, 0);
    __syncthreads();
  }
#undef STGA

  const int b_of = row0 >> 12;
  const int orow = row0 + wr * 64 + lf;
  const int ocl = wc * 64 + (kq << 2);
#pragma unroll
  for (int n = 0; n < 4; ++n) {
    const int cl = ocl + (n << 4);
    const int cb = colL + cl;
    const f32x4 bb = *(const f32x4*)&biasp[cb];
    f32x4 sacc = {0.f, 0.f, 0.f, 0.f};
#pragma unroll
    for (int m = 0; m < 4; ++m) {
      f32x4 v = acc[m][n] + bb;
      if (FUSED && region < 2) {
#pragma unroll
        for (int r = 0; r < 4; ++r) v[r] = 1.0f / (1.0f + expf(-v[r]));
      }
      if (FUSED) {
        bf16x4 o;
#pragma unroll
        for (int r = 0; r < 4; ++r) o[r] = (__bf16)v[r];
        *(bf16x4*)&((__bf16*)Cp)[(size_t)(orow + (m << 4)) * LDQ + col0 + cl] = o;
      } else {
        *(f32x4*)&((float*)Cp)[(size_t)(orow + (m << 4)) * 1024 + col0 + cl] = v;
      }
      sacc += v;
    }
    if (FUSED && region < 2) {
#pragma unroll
      for (int o = 1; o < 16; o <<= 1) {
        sacc[0] += __shfl_xor(sacc[0], o); sacc[1] += __shfl_xor(sacc[1], o);
        sacc[2] += __shfl_xor(sacc[2], o); sacc[3] += __shfl_xor(sacc[3], o);
      }
      if (lf == 0) {
        float* sums = (region == 0) ? qsum : ksum;
#pragma unroll
        for (int r = 0; r < 4; ++r) atomicAdd(&sums[b_of * 1024 + cb + r], sacc[r]);
      }
    }
  }
}

// ---------------- Wo GEMM: 256x128 block, A-through-LDS, B global->regs, (256,2) ---------
template <int FUSED>
__global__ __launch_bounds__(256, 2) void gemm256x128(
    const __bf16* __restrict__ Aq_, const __bf16* __restrict__ Ak_, const __bf16* __restrict__ Av_,
    const __bf16* __restrict__ Wq_, const __bf16* __restrict__ Wk_, const __bf16* __restrict__ Wv_,
    const float* __restrict__ bq_, const float* __restrict__ bk_, const float* __restrict__ bv_,
    void* __restrict__ Cp, float* __restrict__ qsum, float* __restrict__ ksum) {
  __shared__ __bf16 As[256 * 32];
  const int tid = threadIdx.x;
  const int lane = tid & 63, w4 = tid >> 6;
  const int wr = w4 >> 1, wc = w4 & 1;          // 2 x 2 waves; wave tile 128 x 64
  const int lf = lane & 15, kq = lane >> 4;

  constexpr int NCT = FUSED ? 24 : 8;           // 128-col tiles
  constexpr int CPX = (64 * NCT) >> 3;
  const int hwlin = blockIdx.x + blockIdx.y * 64;
  const int swz = (hwlin & 7) * CPX + (hwlin >> 3);
  const int bx = swz / NCT, ct = swz - bx * NCT;
  const int row0 = bx << 8, col0 = ct << 7;
  const int region = FUSED ? (ct >> 3) : 0;
  const int colL = FUSED ? (col0 & 1023) : col0;

  const __bf16* Agl = FUSED ? (region == 0 ? Aq_ : (region == 1 ? Ak_ : Av_)) : Aq_;
  const __bf16* Bgl = FUSED ? (region == 0 ? Wq_ : (region == 1 ? Wk_ : Wv_)) : Wq_;
  const float* biasp = FUSED ? (region == 0 ? bq_ : (region == 1 ? bk_ : bv_)) : bq_;
  const __bf16* Ab_g = Agl + (size_t)row0 * 1024;
  const __bf16* Bb_g = Bgl + (size_t)colL * 1024;

  int arow[4], asrc[4];
#pragma unroll
  for (int i = 0; i < 4; ++i) {
    const int g = i * 256 + tid;
    arow[i] = g >> 2;
    asrc[i] = ((g & 3) ^ ((arow[i] >> 1) & 3)) << 3;
  }
  const int kgsw = (kq ^ ((lf >> 1) & 3)) << 3;
  const int arb = (wr * 128 + lf) * 32 + kgsw;
  const __bf16* Bln = Bb_g + (size_t)(wc * 64 + lf) * 1024 + kq * 8;

  f32x4 acc[8][4] = {};

  for (int t = 0; t < 32; ++t) {
    const int kb = t << 5;
    bf16x8 bfr[4];
#pragma unroll
    for (int n = 0; n < 4; ++n)
      bfr[n] = *(const bf16x8*)(Bln + (size_t)(n << 4) * 1024 + kb);
#pragma unroll
    for (int i = 0; i < 4; ++i)
      gll16(Ab_g + (size_t)arow[i] * 1024 + kb + asrc[i], &As[(i * 256 + tid) * 8]);
    __syncthreads();
    bf16x8 af[8];
#pragma unroll
    for (int m = 0; m < 8; ++m) af[m] = *(const bf16x8*)(As + arb + m * 512);
#pragma unroll
    for (int m = 0; m < 8; ++m)
#pragma unroll
      for (int n = 0; n < 4; ++n)
        acc[m][n] = __builtin_amdgcn_mfma_f32_16x16x32_bf16(bfr[n], af[m], acc[m][n], 0, 0, 0);
    __syncthreads();
  }

  const int b_of = row0 >> 12;
  const int orow = row0 + wr * 128 + lf;
  const int ocl = wc * 64 + (kq << 2);
#pragma unroll
  for (int n = 0; n < 4; ++n) {
    const int cl = ocl + (n << 4);
    const int cb = colL + cl;
    const f32x4 bb = *(const f32x4*)&biasp[cb];
    f32x4 sacc = {0.f, 0.f, 0.f, 0.f};
#pragma unroll
    for (int m = 0; m < 8; ++m) {
      f32x4 v = acc[m][n] + bb;
      if (FUSED && region < 2) {
#pragma unroll
        for (int r = 0; r < 4; ++r) v[r] = 1.0f / (1.0f + expf(-v[r]));
      }
      if (FUSED) {
        bf16x4 o;
#pragma unroll
        for (int r = 0; r < 4; ++r) o[r] = (__bf16)v[r];
        *(bf16x4*)&((__bf16*)Cp)[(size_t)(orow + (m << 4)) * LDQ + col0 + cl] = o;
      } else {
        *(f32x4*)&((float*)Cp)[(size_t)(orow + (m << 4)) * 1024 + col0 + cl] = v;
      }
      sacc += v;
    }
    if (FUSED && region < 2) {
#pragma unroll
      for (int o = 1; o < 16; o <<= 1) {
        sacc[0] += __shfl_xor(sacc[0], o); sacc[1] += __shfl_xor(sacc[1], o);
        sacc[2] += __shfl_xor(sacc[2], o); sacc[3] += __shfl_xor(sacc[3], o);
      }
      if (lf == 0) {
        float* sums = (region == 0) ? qsum : ksum;
#pragma unroll
        for (int r = 0; r < 4; ++r) atomicAdd(&sums[b_of * 1024 + cb + r], sacc[r]);
      }
    }
  }
}

// ---------------- r2: si + qsi/kso (r7/r10-validated) ----------------
__global__ __launch_bounds__(256) void r2_flow(const __bf16* __restrict__ Qp, const __bf16* __restrict__ Kp,
                                               const float* __restrict__ ksum, const float* __restrict__ qsum,
                                               float* __restrict__ si,
                                               float* __restrict__ qsi, float* __restrict__ kso) {
  const int blk = blockIdx.x;
  const int chunk = blk & 15, bh = blk >> 4;
  const int b = bh >> 4, h = bh & 15;
  const int d = threadIdx.x & 63, w = threadIdx.x >> 6;
  __shared__ float ksE[64], qsE[64];
  if (threadIdx.x < 64) ksE[threadIdx.x] = ksum[bh * 64 + threadIdx.x] + EPSc;
  else if (threadIdx.x < 128) qsE[threadIdx.x - 64] = qsum[bh * 64 + threadIdx.x - 64] + EPSc;
  __syncthreads();
  const float kE = ksE[d], qE = qsE[d];
  const size_t base = ((size_t)b * Lc) * LDQ + h * 64 + d;
  const size_t obase = (size_t)bh * Lc;
  float qsia = 0.f, ksoa = 0.f;
  const int l0 = chunk * 256;
  for (int i = w; i < 256; i += 4) {
    const int l = l0 + i;
    const size_t idx = base + (size_t)l * LDQ;
    const float qv = (float)Qp[idx], kvv = (float)Kp[idx];
    float a = (qv + EPSc) * kE;
    float c2 = (kvv + EPSc) * qE;
#pragma unroll
    for (int o = 32; o; o >>= 1) { a += __shfl_xor(a, o); c2 += __shfl_xor(c2, o); }
    const float sil = 1.0f / a, sol = 1.0f / c2;
    if (d == 0) si[obase + l] = sil;
    qsia += qv * sil;
    ksoa += kvv * sol;
  }
  atomicAdd(&qsi[bh * 64 + d], qsia);
  atomicAdd(&kso[bh * 64 + d], ksoa);
}

// ---------------- k5 (+r3 fold): 16-row tiles, 64 barriers (r15-validated) --------
__global__ __launch_bounds__(256) void k5_kv(const __bf16* __restrict__ Kp, const __bf16* __restrict__ Vp,
                                             const float* __restrict__ qsi, float* __restrict__ den,
                                             float* __restrict__ kvout) {
  const int bh = blockIdx.x, chunk = blockIdx.y;  // chunk of 512 rows
  const int b = bh >> 4, h = bh & 15;
  const int tid = threadIdx.x;
  const int dq = (tid >> 4) << 2;
  const int mq = (tid & 15) << 2;
  __shared__ float qsE[64];
  __shared__ float klds[16][64], vlds[16][64];
  if (tid < 64) qsE[tid] = qsi[bh * 64 + tid] + EPSc;
  __syncthreads();
  float acc[4][4] = {};
  float eacc = 0.f;
  const int w = tid >> 6, c = tid & 63;
  const float qE = qsE[c];
  const size_t rowbase = ((size_t)b * Lc + chunk * 512) * LDQ + h * 64;
  for (int i = 0; i < 32; ++i) {                 // 16 rows per iteration
    float kvf[4], vpe[4];
#pragma unroll
    for (int rr = 0; rr < 4; ++rr) {
      const int lrow = i * 16 + rr * 4 + w;      // wave w: rows ≡ w (mod 4), ascending
      const size_t idx = rowbase + (size_t)lrow * LDQ + c;
      kvf[rr] = (float)Kp[idx];
      const float vvf = (float)Vp[idx];
      float c2 = (kvf[rr] + EPSc) * qE;
#pragma unroll
      for (int o = 32; o; o >>= 1) c2 += __shfl_xor(c2, o);
      const float e = expf(fminf(1.0f, fmaxf(-1.0f, c2)));
      if (c == 0) eacc += e;
      vpe[rr] = vvf * e;
    }
    __syncthreads();
#pragma unroll
    for (int rr = 0; rr < 4; ++rr) {
      klds[rr * 4 + w][c] = kvf[rr];
      vlds[rr * 4 + w][c] = vpe[rr];
    }
    __syncthreads();
#pragma unroll
    for (int rr = 0; rr < 16; ++rr) {
      float kr[4], vr[4];
#pragma unroll
      for (int j = 0; j < 4; ++j) { kr[j] = klds[rr][dq + j]; vr[j] = vlds[rr][mq + j]; }
#pragma unroll
      for (int a = 0; a < 4; ++a)
#pragma unroll
        for (int e2 = 0; e2 < 4; ++e2) acc[a][e2] += kr[a] * vr[e2];
    }
  }
  if (c == 0) atomicAdd(&den[bh], eacc);
#pragma unroll
  for (int a = 0; a < 4; ++a)
#pragma unroll
    for (int e2 = 0; e2 < 4; ++e2)
      atomicAdd(&kvout[(size_t)bh * 4096 + (dq + a) * 64 + mq + e2], acc[a][e2]);
}

// ---------------- k6 (+r3 sa fold): x = (q @ kv_un) * si * sigmoid(a) * sden, MFMA -------
__global__ __launch_bounds__(256) void k6_x(const __bf16* __restrict__ Qp,
                                            const float* __restrict__ kvin, const float* __restrict__ si,
                                            const float* __restrict__ kso, const float* __restrict__ den,
                                            __bf16* __restrict__ Xb) {
  const int bh = blockIdx.x, chunk = blockIdx.y;  // chunk of 256 rows
  const int b = bh >> 4, h = bh & 15;
  const int tid = threadIdx.x, lane = tid & 63, w = tid >> 6;
  const int lf = lane & 15, kq = lane >> 4;
  const float sden = 4096.0f / den[bh];
  f32x4 kE0a = *(const f32x4*)&kso[bh * 64 + kq * 8];
  f32x4 kE0b = *(const f32x4*)&kso[bh * 64 + kq * 8 + 4];
  f32x4 kE1a = *(const f32x4*)&kso[bh * 64 + 32 + kq * 8];
  f32x4 kE1b = *(const f32x4*)&kso[bh * 64 + 32 + kq * 8 + 4];
#pragma unroll
  for (int j = 0; j < 4; ++j) { kE0a[j] += EPSc; kE0b[j] += EPSc; kE1a[j] += EPSc; kE1b[j] += EPSc; }
  __shared__ float ktl[64][66];                  // ktl[m][d]
  for (int e = tid; e < 4096; e += 256)          // e = d*64 + m
    ktl[e & 63][e >> 6] = kvin[(size_t)bh * 4096 + e];
  __syncthreads();
  bf16x8 kh[4][2], kl[4][2];
#pragma unroll
  for (int mi = 0; mi < 4; ++mi)
#pragma unroll
    for (int hf = 0; hf < 2; ++hf) {
      const float* p = &ktl[mi * 16 + lf][hf * 32 + kq * 8];
      bf16x8 hi, lo;
#pragma unroll
      for (int j = 0; j < 8; ++j) {
        const float f = p[j];
        hi[j] = (__bf16)f;
        lo[j] = (__bf16)(f - (float)hi[j]);
      }
      kh[mi][hf] = hi; kl[mi][hf] = lo;
    }
  const size_t bL = (size_t)b * Lc;
  const size_t obase = (size_t)bh * Lc;
#pragma unroll
  for (int gi = 0; gi < 4; ++gi) {
    const int lrow = chunk * 256 + (w * 4 + gi) * 16 + lf;
    const size_t qb = (bL + lrow) * LDQ + h * 64;
    const bf16x8 qf0 = *(const bf16x8*)(Qp + qb + kq * 8);
    const bf16x8 qf1 = *(const bf16x8*)(Qp + qb + 32 + kq * 8);
    float a = 0.f;
#pragma unroll
    for (int j = 0; j < 4; ++j) {
      a += ((float)qf0[j] + EPSc) * kE0a[j];
      a += ((float)qf0[4 + j] + EPSc) * kE0b[j];
      a += ((float)qf1[j] + EPSc) * kE1a[j];
      a += ((float)qf1[4 + j] + EPSc) * kE1b[j];
    }
    a += __shfl_xor(a, 16);
    a += __shfl_xor(a, 32);
    const float sav = 1.0f / (1.0f + expf(-a));
    const float sc = si[obase + lrow] * sav * sden;
    f32x4 acc[4] = {};
#pragma unroll
    for (int mi = 0; mi < 4; ++mi) {
      acc[mi] = __builtin_amdgcn_mfma_f32_16x16x32_bf16(kh[mi][0], qf0, acc[mi], 0, 0, 0);
      acc[mi] = __builtin_amdgcn_mfma_f32_16x16x32_bf16(kh[mi][1], qf1, acc[mi], 0, 0, 0);
      acc[mi] = __builtin_amdgcn_mfma_f32_16x16x32_bf16(kl[mi][0], qf0, acc[mi], 0, 0, 0);
      acc[mi] = __builtin_amdgcn_mfma_f32_16x16x32_bf16(kl[mi][1], qf1, acc[mi], 0, 0, 0);
    }
#pragma unroll
    for (int mi = 0; mi < 4; ++mi) {
      bf16x4 o;
#pragma unroll
      for (int r = 0; r < 4; ++r) o[r] = (__bf16)(acc[mi][r] * sc);
      *(bf16x4*)&Xb[(bL + lrow) * Dc + h * 64 + mi * 16 + (kq << 2)] = o;
    }
  }
}

// ---------------- host ----------------
extern "C" void kernel_launch(void* const* d_in, const int* in_sizes, int n_in,
                              void* d_out, int out_size, void* d_ws, size_t ws_size,
                              hipStream_t stream) {
  const float* Qin = (const float*)d_in[0];
  const float* Kin = (const float*)d_in[1];
  const float* Vin = (const float*)d_in[2];
  const float* Wq = (const float*)d_in[3];
  const float* bq = (const float*)d_in[4];
  const float* Wk = (const float*)d_in[5];
  const float* bk = (const float*)d_in[6];
  const float* Wv = (const float*)d_in[7];
  const float* bv = (const float*)d_in[8];
  const float* Wo = (const float*)d_in[9];
  const float* bo = (const float*)d_in[10];

  const size_t MD = (size_t)Mc * Dc;
  __bf16* Aq = (__bf16*)d_ws;
  __bf16* Ak = Aq + MD;
  __bf16* Av = Ak + MD;
  __bf16* Wqt = Av + MD;
  __bf16* Wkt = Wqt + (size_t)Dc * Dc;
  __bf16* Wvt = Wkt + (size_t)Dc * Dc;
  __bf16* Wot = Wvt + (size_t)Dc * Dc;
  __bf16* QKV = Wot + (size_t)Dc * Dc;          // [M][3072]
  float* F = (float*)(QKV + (size_t)Mc * LDQ);
  float* ksum = F;              // 4096
  float* qsum = ksum + 4096;    // 4096
  float* kso = qsum + 4096;     // 4096
  float* qsi = kso + 4096;      // 4096
  float* den = qsi + 4096;      // 64
  float* kv = den + 64;         // 64*4096 (un-normalized)
  float* si = kv + 262144;
  __bf16* Xb = Aq;              // reuse Aq (dead after QKV GEMM)

  hipMemsetAsync(F, 0, (size_t)(4 * 4096 + 64 + 262144) * sizeof(float), stream);

  conv3<<<dim3((int)(MD / 4 / 256), 3), 256, 0, stream>>>(Qin, Kin, Vin, Aq);
  wt_conv4<<<dim3(32, 32, 4), dim3(32, 8), 0, stream>>>(Wq, Wk, Wv, Wo, Wqt);

  // fused grouped QKV projection: 3072 blocks of 128x128, A-LDS dbuf, B direct
  gemm128p<1><<<dim3(128, 24), 256, 0, stream>>>(Aq, Ak, Av, Wqt, Wkt, Wvt,
                                                 bq, bk, bv, QKV, qsum, ksum);

  const __bf16* Qp = QKV;
  const __bf16* Kp = QKV + 1024;
  const __bf16* Vp = QKV + 2048;
  r2_flow<<<1024, 256, 0, stream>>>(Qp, Kp, ksum, qsum, si, qsi, kso);
  k5_kv<<<dim3(64, 8), 256, 0, stream>>>(Kp, Vp, qsi, den, kv);
  k6_x<<<dim3(64, 16), 256, 0, stream>>>(Qp, kv, si, kso, den, Xb);

  // output projection: fp32 out, 512 blocks of 256x128, B direct
  gemm256x128<0><<<dim3(64, 8), 256, 0, stream>>>(Xb, nullptr, nullptr, Wot, nullptr, nullptr,
                                                  bo, nullptr, nullptr, d_out, nullptr, nullptr);
}

// Round 19
// 409.212 us; speedup vs baseline: 1.2274x; 1.2274x over previous
//
#include <hip/hip_runtime.h>

#define Bc 4
#define Lc 4096
#define Dc 1024
#define LDQ 3072
#define Mc (Bc*Lc)
#define EPSc 1e-6f

typedef __bf16 bf16x8 __attribute__((ext_vector_type(8)));
typedef __bf16 bf16x4 __attribute__((ext_vector_type(4)));
typedef float f32x4 __attribute__((ext_vector_type(4)));

typedef __attribute__((address_space(3))) void lds_vt;
typedef const __attribute__((address_space(1))) void gbl_vt;

__device__ __forceinline__ void gll16(const void* g, void* l) {
  __builtin_amdgcn_global_load_lds((gbl_vt*)g, (lds_vt*)l, 16, 0, 0);
}

// ---------------- fused converts (validated) ----------------
__global__ __launch_bounds__(256) void conv3(const float* __restrict__ Q, const float* __restrict__ K,
                                             const float* __restrict__ V, __bf16* __restrict__ Y) {
  const float* src = (blockIdx.y == 0) ? Q : (blockIdx.y == 1) ? K : V;
  __bf16* dst = Y + (size_t)blockIdx.y * ((size_t)Mc * Dc);
  const int i = blockIdx.x * 256 + threadIdx.x;
  const float4 v = ((const float4*)src)[i];
  bf16x4 o;
  o[0] = (__bf16)v.x; o[1] = (__bf16)v.y; o[2] = (__bf16)v.z; o[3] = (__bf16)v.w;
  ((bf16x4*)dst)[i] = o;
}

__global__ __launch_bounds__(256) void wt_conv4(const float* __restrict__ W0, const float* __restrict__ W1,
                                                const float* __restrict__ W2, const float* __restrict__ W3,
                                                __bf16* __restrict__ T) {
  const float* W = (blockIdx.z == 0) ? W0 : (blockIdx.z == 1) ? W1 : (blockIdx.z == 2) ? W2 : W3;
  __bf16* Wt = T + (size_t)blockIdx.z * ((size_t)Dc * Dc);
  __shared__ float t[32][33];
  const int n0 = blockIdx.x << 5, k0 = blockIdx.y << 5;
  const int tx = threadIdx.x, ty = threadIdx.y;  // block (32,8)
#pragma unroll
  for (int i = 0; i < 4; ++i)
    t[ty + 8 * i][tx] = W[(size_t)(k0 + ty + 8 * i) * Dc + n0 + tx];
  __syncthreads();
#pragma unroll
  for (int i = 0; i < 4; ++i)
    Wt[(size_t)(n0 + ty + 8 * i) * Dc + k0 + tx] = (__bf16)t[tx][ty + 8 * i];
}

// ---------------- QKV GEMM: 128x128, BK=32, dbuf 2-phase (r15/r17-validated) -------------
// NOTE: only the 4x4-frag structure tolerates 4 blocks/CU — 64 AGPR acc + ~56 VGPR = 120
// < 128 budget at (256,4). The 8x4-frag kernel at (256,4) SPILLS acc to scratch (r16).
// B-direct-to-regs regressed (r18: per-step L2 latency on the MFMA critical path).
template <int FUSED>
__global__ __launch_bounds__(256, 4) void gemm128p(
    const __bf16* __restrict__ Aq_, const __bf16* __restrict__ Ak_, const __bf16* __restrict__ Av_,
    const __bf16* __restrict__ Wq_, const __bf16* __restrict__ Wk_, const __bf16* __restrict__ Wv_,
    const float* __restrict__ bq_, const float* __restrict__ bk_, const float* __restrict__ bv_,
    void* __restrict__ Cp, float* __restrict__ qsum, float* __restrict__ ksum) {
  __shared__ __bf16 As[2][128 * 32];
  __shared__ __bf16 Bs[2][128 * 32];
  const int tid = threadIdx.x;
  const int lane = tid & 63, w4 = tid >> 6;
  const int wr = w4 >> 1, wc = w4 & 1;          // 2 x 2 waves, 64x64 each
  const int lf = lane & 15, kq = lane >> 4;

  constexpr int NCT = FUSED ? 24 : 8;
  constexpr int CPX = (128 * NCT) >> 3;
  const int hwlin = blockIdx.x + (blockIdx.y << 7);
  const int swz = (hwlin & 7) * CPX + (hwlin >> 3);
  const int bx = swz / NCT, ct = swz - bx * NCT;
  const int row0 = bx << 7, col0 = ct << 7;
  const int region = FUSED ? (ct >> 3) : 0;
  const int colL = FUSED ? (col0 & 1023) : col0;

  const __bf16* Agl = FUSED ? (region == 0 ? Aq_ : (region == 1 ? Ak_ : Av_)) : Aq_;
  const __bf16* Bgl = FUSED ? (region == 0 ? Wq_ : (region == 1 ? Wk_ : Wv_)) : Wq_;
  const float* biasp = FUSED ? (region == 0 ? bq_ : (region == 1 ? bk_ : bv_)) : bq_;
  const __bf16* Ab_g = Agl + (size_t)row0 * 1024;
  const __bf16* Bb_g = Bgl + (size_t)colL * 1024;

  const int srow = (w4 << 5) + (lane >> 2);
  const int sgd = lane & 3;
  const int ssrc = (sgd ^ ((lane >> 3) & 3)) << 3;
  const size_t aoff0 = (size_t)srow * 1024 + ssrc;
  const size_t aoff1 = (size_t)(srow + 16) * 1024 + ssrc;
  const int ldst0 = srow * 32 + (sgd << 3);
  const int ldst1 = (srow + 16) * 32 + (sgd << 3);

  const int kgsw = (kq ^ ((lf >> 1) & 3)) << 3;
  const int arb = (wr * 64 + lf) * 32 + kgsw;
  const int brb = (wc * 64 + lf) * 32 + kgsw;

#define STGP(T, U) do { \
    const int kb_ = (T) << 5; \
    gll16(Ab_g + aoff0 + kb_, &As[U][ldst0]); \
    gll16(Ab_g + aoff1 + kb_, &As[U][ldst1]); \
    gll16(Bb_g + aoff0 + kb_, &Bs[U][ldst0]); \
    gll16(Bb_g + aoff1 + kb_, &Bs[U][ldst1]); \
  } while (0)

  f32x4 acc[4][4] = {};

  STGP(0, 0);
  __syncthreads();

  for (int t = 0; t < 32; ++t) {
    const int u = t & 1;
    if (t < 31) STGP(t + 1, u ^ 1);   // streams during compute; drained at syncthreads
    bf16x8 af[4], bfr[4];
#pragma unroll
    for (int m = 0; m < 4; ++m) af[m] = *(const bf16x8*)(&As[u][0] + arb + m * 512);
#pragma unroll
    for (int n = 0; n < 4; ++n) bfr[n] = *(const bf16x8*)(&Bs[u][0] + brb + n * 512);
#pragma unroll
    for (int m = 0; m < 4; ++m)
#pragma unroll
      for (int n = 0; n < 4; ++n)
        acc[m][n] = __builtin_amdgcn_mfma_f32_16x16x32_bf16(bfr[n], af[m], acc[m][n], 0, 0, 0);
    __syncthreads();
  }
#undef STGP

  const int b_of = row0 >> 12;
  const int orow = row0 + wr * 64 + lf;
  const int ocl = wc * 64 + (kq << 2);
#pragma unroll
  for (int n = 0; n < 4; ++n) {
    const int cl = ocl + (n << 4);
    const int cb = colL + cl;
    const f32x4 bb = *(const f32x4*)&biasp[cb];
    f32x4 sacc = {0.f, 0.f, 0.f, 0.f};
#pragma unroll
    for (int m = 0; m < 4; ++m) {
      f32x4 v = acc[m][n] + bb;
      if (FUSED && region < 2) {
#pragma unroll
        for (int r = 0; r < 4; ++r) v[r] = 1.0f / (1.0f + expf(-v[r]));
      }
      if (FUSED) {
        bf16x4 o;
#pragma unroll
        for (int r = 0; r < 4; ++r) o[r] = (__bf16)v[r];
        *(bf16x4*)&((__bf16*)Cp)[(size_t)(orow + (m << 4)) * LDQ + col0 + cl] = o;
      } else {
        *(f32x4*)&((float*)Cp)[(size_t)(orow + (m << 4)) * 1024 + col0 + cl] = v;
      }
      sacc += v;
    }
    if (FUSED && region < 2) {
#pragma unroll
      for (int o = 1; o < 16; o <<= 1) {
        sacc[0] += __shfl_xor(sacc[0], o); sacc[1] += __shfl_xor(sacc[1], o);
        sacc[2] += __shfl_xor(sacc[2], o); sacc[3] += __shfl_xor(sacc[3], o);
      }
      if (lf == 0) {
        float* sums = (region == 0) ? qsum : ksum;
#pragma unroll
        for (int r = 0; r < 4; ++r) atomicAdd(&sums[b_of * 1024 + cb + r], sacc[r]);
      }
    }
  }
}

// ---------------- Wo GEMM: 256x128 block, 128x64 per wave (r12-validated, (256,2) ONLY) ---
template <int FUSED>
__global__ __launch_bounds__(256, 2) void gemm256x128(
    const __bf16* __restrict__ Aq_, const __bf16* __restrict__ Ak_, const __bf16* __restrict__ Av_,
    const __bf16* __restrict__ Wq_, const __bf16* __restrict__ Wk_, const __bf16* __restrict__ Wv_,
    const float* __restrict__ bq_, const float* __restrict__ bk_, const float* __restrict__ bv_,
    void* __restrict__ Cp, float* __restrict__ qsum, float* __restrict__ ksum) {
  __shared__ __bf16 As[256 * 32];
  __shared__ __bf16 Bs[128 * 32];
  const int tid = threadIdx.x;
  const int lane = tid & 63, w4 = tid >> 6;
  const int wr = w4 >> 1, wc = w4 & 1;          // 2 x 2 waves; wave tile 128 x 64
  const int lf = lane & 15, kq = lane >> 4;

  constexpr int NCT = FUSED ? 24 : 8;           // 128-col tiles
  constexpr int CPX = (64 * NCT) >> 3;
  const int hwlin = blockIdx.x + blockIdx.y * 64;
  const int swz = (hwlin & 7) * CPX + (hwlin >> 3);
  const int bx = swz / NCT, ct = swz - bx * NCT;
  const int row0 = bx << 8, col0 = ct << 7;
  const int region = FUSED ? (ct >> 3) : 0;
  const int colL = FUSED ? (col0 & 1023) : col0;

  const __bf16* Agl = FUSED ? (region == 0 ? Aq_ : (region == 1 ? Ak_ : Av_)) : Aq_;
  const __bf16* Bgl = FUSED ? (region == 0 ? Wq_ : (region == 1 ? Wk_ : Wv_)) : Wq_;
  const float* biasp = FUSED ? (region == 0 ? bq_ : (region == 1 ? bk_ : bv_)) : bq_;
  const __bf16* Ab_g = Agl + (size_t)row0 * 1024;
  const __bf16* Bb_g = Bgl + (size_t)colL * 1024;

  int arow[4], asrc[4];
#pragma unroll
  for (int i = 0; i < 4; ++i) {
    const int g = i * 256 + tid;
    arow[i] = g >> 2;
    asrc[i] = ((g & 3) ^ ((arow[i] >> 1) & 3)) << 3;
  }
  const int kgsw = (kq ^ ((lf >> 1) & 3)) << 3;
  const int arb = (wr * 128 + lf) * 32 + kgsw;
  const int brb = (wc * 64 + lf) * 32 + kgsw;

  f32x4 acc[8][4] = {};

  for (int t = 0; t < 32; ++t) {
    const int kb = t << 5;
#pragma unroll
    for (int i = 0; i < 4; ++i)
      gll16(Ab_g + (size_t)arow[i] * 1024 + kb + asrc[i], &As[(i * 256 + tid) * 8]);
#pragma unroll
    for (int i = 0; i < 2; ++i)
      gll16(Bb_g + (size_t)arow[i] * 1024 + kb + asrc[i], &Bs[(i * 256 + tid) * 8]);
    __syncthreads();
    bf16x8 af[8], bfr[4];
#pragma unroll
    for (int m = 0; m < 8; ++m) af[m] = *(const bf16x8*)(As + arb + m * 512);
#pragma unroll
    for (int n = 0; n < 4; ++n) bfr[n] = *(const bf16x8*)(Bs + brb + n * 512);
#pragma unroll
    for (int m = 0; m < 8; ++m)
#pragma unroll
      for (int n = 0; n < 4; ++n)
        acc[m][n] = __builtin_amdgcn_mfma_f32_16x16x32_bf16(bfr[n], af[m], acc[m][n], 0, 0, 0);
    __syncthreads();
  }

  const int b_of = row0 >> 12;
  const int orow = row0 + wr * 128 + lf;
  const int ocl = wc * 64 + (kq << 2);
#pragma unroll
  for (int n = 0; n < 4; ++n) {
    const int cl = ocl + (n << 4);
    const int cb = colL + cl;
    const f32x4 bb = *(const f32x4*)&biasp[cb];
    f32x4 sacc = {0.f, 0.f, 0.f, 0.f};
#pragma unroll
    for (int m = 0; m < 8; ++m) {
      f32x4 v = acc[m][n] + bb;
      if (FUSED && region < 2) {
#pragma unroll
        for (int r = 0; r < 4; ++r) v[r] = 1.0f / (1.0f + expf(-v[r]));
      }
      if (FUSED) {
        bf16x4 o;
#pragma unroll
        for (int r = 0; r < 4; ++r) o[r] = (__bf16)v[r];
        *(bf16x4*)&((__bf16*)Cp)[(size_t)(orow + (m << 4)) * LDQ + col0 + cl] = o;
      } else {
        *(f32x4*)&((float*)Cp)[(size_t)(orow + (m << 4)) * 1024 + col0 + cl] = v;
      }
      sacc += v;
    }
    if (FUSED && region < 2) {
#pragma unroll
      for (int o = 1; o < 16; o <<= 1) {
        sacc[0] += __shfl_xor(sacc[0], o); sacc[1] += __shfl_xor(sacc[1], o);
        sacc[2] += __shfl_xor(sacc[2], o); sacc[3] += __shfl_xor(sacc[3], o);
      }
      if (lf == 0) {
        float* sums = (region == 0) ? qsum : ksum;
#pragma unroll
        for (int r = 0; r < 4; ++r) atomicAdd(&sums[b_of * 1024 + cb + r], sacc[r]);
      }
    }
  }
}

// ---------------- r2: si + qsi/kso (r7/r10-validated) ----------------
__global__ __launch_bounds__(256) void r2_flow(const __bf16* __restrict__ Qp, const __bf16* __restrict__ Kp,
                                               const float* __restrict__ ksum, const float* __restrict__ qsum,
                                               float* __restrict__ si,
                                               float* __restrict__ qsi, float* __restrict__ kso) {
  const int blk = blockIdx.x;
  const int chunk = blk & 15, bh = blk >> 4;
  const int b = bh >> 4, h = bh & 15;
  const int d = threadIdx.x & 63, w = threadIdx.x >> 6;
  __shared__ float ksE[64], qsE[64];
  if (threadIdx.x < 64) ksE[threadIdx.x] = ksum[bh * 64 + threadIdx.x] + EPSc;
  else if (threadIdx.x < 128) qsE[threadIdx.x - 64] = qsum[bh * 64 + threadIdx.x - 64] + EPSc;
  __syncthreads();
  const float kE = ksE[d], qE = qsE[d];
  const size_t base = ((size_t)b * Lc) * LDQ + h * 64 + d;
  const size_t obase = (size_t)bh * Lc;
  float qsia = 0.f, ksoa = 0.f;
  const int l0 = chunk * 256;
  for (int i = w; i < 256; i += 4) {
    const int l = l0 + i;
    const size_t idx = base + (size_t)l * LDQ;
    const float qv = (float)Qp[idx], kvv = (float)Kp[idx];
    float a = (qv + EPSc) * kE;
    float c2 = (kvv + EPSc) * qE;
#pragma unroll
    for (int o = 32; o; o >>= 1) { a += __shfl_xor(a, o); c2 += __shfl_xor(c2, o); }
    const float sil = 1.0f / a, sol = 1.0f / c2;
    if (d == 0) si[obase + l] = sil;
    qsia += qv * sil;
    ksoa += kvv * sol;
  }
  atomicAdd(&qsi[bh * 64 + d], qsia);
  atomicAdd(&kso[bh * 64 + d], ksoa);
}

// ---------------- k5 (+r3 fold): 16-row tiles, 64 barriers (r15-validated) --------
__global__ __launch_bounds__(256) void k5_kv(const __bf16* __restrict__ Kp, const __bf16* __restrict__ Vp,
                                             const float* __restrict__ qsi, float* __restrict__ den,
                                             float* __restrict__ kvout) {
  const int bh = blockIdx.x, chunk = blockIdx.y;  // chunk of 512 rows
  const int b = bh >> 4, h = bh & 15;
  const int tid = threadIdx.x;
  const int dq = (tid >> 4) << 2;
  const int mq = (tid & 15) << 2;
  __shared__ float qsE[64];
  __shared__ float klds[16][64], vlds[16][64];
  if (tid < 64) qsE[tid] = qsi[bh * 64 + tid] + EPSc;
  __syncthreads();
  float acc[4][4] = {};
  float eacc = 0.f;
  const int w = tid >> 6, c = tid & 63;
  const float qE = qsE[c];
  const size_t rowbase = ((size_t)b * Lc + chunk * 512) * LDQ + h * 64;
  for (int i = 0; i < 32; ++i) {                 // 16 rows per iteration
    float kvf[4], vpe[4];
#pragma unroll
    for (int rr = 0; rr < 4; ++rr) {
      const int lrow = i * 16 + rr * 4 + w;      // wave w: rows ≡ w (mod 4), ascending
      const size_t idx = rowbase + (size_t)lrow * LDQ + c;
      kvf[rr] = (float)Kp[idx];
      const float vvf = (float)Vp[idx];
      float c2 = (kvf[rr] + EPSc) * qE;
#pragma unroll
      for (int o = 32; o; o >>= 1) c2 += __shfl_xor(c2, o);
      const float e = expf(fminf(1.0f, fmaxf(-1.0f, c2)));
      if (c == 0) eacc += e;
      vpe[rr] = vvf * e;
    }
    __syncthreads();
#pragma unroll
    for (int rr = 0; rr < 4; ++rr) {
      klds[rr * 4 + w][c] = kvf[rr];
      vlds[rr * 4 + w][c] = vpe[rr];
    }
    __syncthreads();
#pragma unroll
    for (int rr = 0; rr < 16; ++rr) {
      float kr[4], vr[4];
#pragma unroll
      for (int j = 0; j < 4; ++j) { kr[j] = klds[rr][dq + j]; vr[j] = vlds[rr][mq + j]; }
#pragma unroll
      for (int a = 0; a < 4; ++a)
#pragma unroll
        for (int e2 = 0; e2 < 4; ++e2) acc[a][e2] += kr[a] * vr[e2];
    }
  }
  if (c == 0) atomicAdd(&den[bh], eacc);
#pragma unroll
  for (int a = 0; a < 4; ++a)
#pragma unroll
    for (int e2 = 0; e2 < 4; ++e2)
      atomicAdd(&kvout[(size_t)bh * 4096 + (dq + a) * 64 + mq + e2], acc[a][e2]);
}

// ---------------- k6 (+r3 sa fold): x = (q @ kv_un) * si * sigmoid(a) * sden, MFMA -------
__global__ __launch_bounds__(256) void k6_x(const __bf16* __restrict__ Qp,
                                            const float* __restrict__ kvin, const float* __restrict__ si,
                                            const float* __restrict__ kso, const float* __restrict__ den,
                                            __bf16* __restrict__ Xb) {
  const int bh = blockIdx.x, chunk = blockIdx.y;  // chunk of 256 rows
  const int b = bh >> 4, h = bh & 15;
  const int tid = threadIdx.x, lane = tid & 63, w = tid >> 6;
  const int lf = lane & 15, kq = lane >> 4;
  const float sden = 4096.0f / den[bh];
  f32x4 kE0a = *(const f32x4*)&kso[bh * 64 + kq * 8];
  f32x4 kE0b = *(const f32x4*)&kso[bh * 64 + kq * 8 + 4];
  f32x4 kE1a = *(const f32x4*)&kso[bh * 64 + 32 + kq * 8];
  f32x4 kE1b = *(const f32x4*)&kso[bh * 64 + 32 + kq * 8 + 4];
#pragma unroll
  for (int j = 0; j < 4; ++j) { kE0a[j] += EPSc; kE0b[j] += EPSc; kE1a[j] += EPSc; kE1b[j] += EPSc; }
  __shared__ float ktl[64][66];                  // ktl[m][d]
  for (int e = tid; e < 4096; e += 256)          // e = d*64 + m
    ktl[e & 63][e >> 6] = kvin[(size_t)bh * 4096 + e];
  __syncthreads();
  bf16x8 kh[4][2], kl[4][2];
#pragma unroll
  for (int mi = 0; mi < 4; ++mi)
#pragma unroll
    for (int hf = 0; hf < 2; ++hf) {
      const float* p = &ktl[mi * 16 + lf][hf * 32 + kq * 8];
      bf16x8 hi, lo;
#pragma unroll
      for (int j = 0; j < 8; ++j) {
        const float f = p[j];
        hi[j] = (__bf16)f;
        lo[j] = (__bf16)(f - (float)hi[j]);
      }
      kh[mi][hf] = hi; kl[mi][hf] = lo;
    }
  const size_t bL = (size_t)b * Lc;
  const size_t obase = (size_t)bh * Lc;
#pragma unroll
  for (int gi = 0; gi < 4; ++gi) {
    const int lrow = chunk * 256 + (w * 4 + gi) * 16 + lf;
    const size_t qb = (bL + lrow) * LDQ + h * 64;
    const bf16x8 qf0 = *(const bf16x8*)(Qp + qb + kq * 8);
    const bf16x8 qf1 = *(const bf16x8*)(Qp + qb + 32 + kq * 8);
    float a = 0.f;
#pragma unroll
    for (int j = 0; j < 4; ++j) {
      a += ((float)qf0[j] + EPSc) * kE0a[j];
      a += ((float)qf0[4 + j] + EPSc) * kE0b[j];
      a += ((float)qf1[j] + EPSc) * kE1a[j];
      a += ((float)qf1[4 + j] + EPSc) * kE1b[j];
    }
    a += __shfl_xor(a, 16);
    a += __shfl_xor(a, 32);
    const float sav = 1.0f / (1.0f + expf(-a));
    const float sc = si[obase + lrow] * sav * sden;
    f32x4 acc[4] = {};
#pragma unroll
    for (int mi = 0; mi < 4; ++mi) {
      acc[mi] = __builtin_amdgcn_mfma_f32_16x16x32_bf16(kh[mi][0], qf0, acc[mi], 0, 0, 0);
      acc[mi] = __builtin_amdgcn_mfma_f32_16x16x32_bf16(kh[mi][1], qf1, acc[mi], 0, 0, 0);
      acc[mi] = __builtin_amdgcn_mfma_f32_16x16x32_bf16(kl[mi][0], qf0, acc[mi], 0, 0, 0);
      acc[mi] = __builtin_amdgcn_mfma_f32_16x16x32_bf16(kl[mi][1], qf1, acc[mi], 0, 0, 0);
    }
#pragma unroll
    for (int mi = 0; mi < 4; ++mi) {
      bf16x4 o;
#pragma unroll
      for (int r = 0; r < 4; ++r) o[r] = (__bf16)(acc[mi][r] * sc);
      *(bf16x4*)&Xb[(bL + lrow) * Dc + h * 64 + mi * 16 + (kq << 2)] = o;
    }
  }
}

// ---------------- host ----------------
extern "C" void kernel_launch(void* const* d_in, const int* in_sizes, int n_in,
                              void* d_out, int out_size, void* d_ws, size_t ws_size,
                              hipStream_t stream) {
  const float* Qin = (const float*)d_in[0];
  const float* Kin = (const float*)d_in[1];
  const float* Vin = (const float*)d_in[2];
  const float* Wq = (const float*)d_in[3];
  const float* bq = (const float*)d_in[4];
  const float* Wk = (const float*)d_in[5];
  const float* bk = (const float*)d_in[6];
  const float* Wv = (const float*)d_in[7];
  const float* bv = (const float*)d_in[8];
  const float* Wo = (const float*)d_in[9];
  const float* bo = (const float*)d_in[10];

  const size_t MD = (size_t)Mc * Dc;
  __bf16* Aq = (__bf16*)d_ws;
  __bf16* Ak = Aq + MD;
  __bf16* Av = Ak + MD;
  __bf16* Wqt = Av + MD;
  __bf16* Wkt = Wqt + (size_t)Dc * Dc;
  __bf16* Wvt = Wkt + (size_t)Dc * Dc;
  __bf16* Wot = Wvt + (size_t)Dc * Dc;
  __bf16* QKV = Wot + (size_t)Dc * Dc;          // [M][3072]
  float* F = (float*)(QKV + (size_t)Mc * LDQ);
  float* ksum = F;              // 4096
  float* qsum = ksum + 4096;    // 4096
  float* kso = qsum + 4096;     // 4096
  float* qsi = kso + 4096;      // 4096
  float* den = qsi + 4096;      // 64
  float* kv = den + 64;         // 64*4096 (un-normalized)
  float* si = kv + 262144;
  __bf16* Xb = Aq;              // reuse Aq (dead after QKV GEMM)

  hipMemsetAsync(F, 0, (size_t)(4 * 4096 + 64 + 262144) * sizeof(float), stream);

  conv3<<<dim3((int)(MD / 4 / 256), 3), 256, 0, stream>>>(Qin, Kin, Vin, Aq);
  wt_conv4<<<dim3(32, 32, 4), dim3(32, 8), 0, stream>>>(Wq, Wk, Wv, Wo, Wqt);

  // fused grouped QKV projection: 3072 blocks of 128x128, BK=32, 2-phase dbuf
  gemm128p<1><<<dim3(128, 24), 256, 0, stream>>>(Aq, Ak, Av, Wqt, Wkt, Wvt,
                                                 bq, bk, bv, QKV, qsum, ksum);

  const __bf16* Qp = QKV;
  const __bf16* Kp = QKV + 1024;
  const __bf16* Vp = QKV + 2048;
  r2_flow<<<1024, 256, 0, stream>>>(Qp, Kp, ksum, qsum, si, qsi, kso);
  k5_kv<<<dim3(64, 8), 256, 0, stream>>>(Kp, Vp, qsi, den, kv);
  k6_x<<<dim3(64, 16), 256, 0, stream>>>(Qp, kv, si, kso, den, Xb);

  // output projection: fp32 out, 512 blocks of 256x128 (r12-validated)
  gemm256x128<0><<<dim3(64, 8), 256, 0, stream>>>(Xb, nullptr, nullptr, Wot, nullptr, nullptr,
                                                  bo, nullptr, nullptr, d_out, nullptr, nullptr);
}